// Round 2
// baseline (321.791 us; speedup 1.0000x reference)
//
#include <hip/hip_runtime.h>
#include <hip/hip_bf16.h>

// Problem constants (from reference setup_inputs):
//   S=272 sensors, B=128, T=1024, J=128 channels, H=32 harmonics.
//   X:[S,B,T] f32, sensor_locs:[S,2] f32, fourier_weights:[J,H,H,2] f32.
// Key identity: einsum('si,sjk->sjk', softmax(attn), X) = (sum_i softmax_i) * X
// => per-sensor scalar scale (≈1.0 up to fp32 rounding), then elementwise scale.

#define NS 272
#define NJ 128
#define KL 1024          // H*H
#define BT_LOG2_F4 15    // B*T floats = 2^17 -> 2^15 float4 per sensor
#define N4 8912896       // S * B * T / 4

__global__ __launch_bounds__(256) void scale_kernel(
    const float* __restrict__ locs,   // [S,2]
    const float* __restrict__ W,      // [J,H,H,2]
    float* __restrict__ scale)        // [S] out
{
    __shared__ float cosv[2][KL];
    __shared__ float sinv[2][KL];
    __shared__ float mm[4][4];   // per-wave min/max scratch
    __shared__ float wred[4];    // cross-wave reduction scratch

    const int tid  = threadIdx.x;
    const int lane = tid & 63;
    const int wave = tid >> 6;
    const int sensLocal = tid >> 7;            // 0 or 1
    const int s = blockIdx.x * 2 + sensLocal;  // 136 blocks * 2 = 272
    const int jt = tid & 127;                  // this thread's output channel

    // ---- 1. block-wide min/max of sensor_locs over S=272 entries ----
    float lx = 1e30f, ly = 1e30f, hx = -1e30f, hy = -1e30f;
    for (int i = tid; i < NS; i += 256) {
        float x = locs[2 * i], y = locs[2 * i + 1];
        lx = fminf(lx, x); hx = fmaxf(hx, x);
        ly = fminf(ly, y); hy = fmaxf(hy, y);
    }
#pragma unroll
    for (int off = 32; off; off >>= 1) {
        lx = fminf(lx, __shfl_xor(lx, off));
        hx = fmaxf(hx, __shfl_xor(hx, off));
        ly = fminf(ly, __shfl_xor(ly, off));
        hy = fmaxf(hy, __shfl_xor(hy, off));
    }
    if (lane == 0) { mm[wave][0] = lx; mm[wave][1] = hx; mm[wave][2] = ly; mm[wave][3] = hy; }
    __syncthreads();
    lx = fminf(fminf(mm[0][0], mm[1][0]), fminf(mm[2][0], mm[3][0]));
    hx = fmaxf(fmaxf(mm[0][1], mm[1][1]), fmaxf(mm[2][1], mm[3][1]));
    ly = fminf(fminf(mm[0][2], mm[1][2]), fminf(mm[2][2], mm[3][2]));
    hy = fmaxf(fmaxf(mm[0][3], mm[1][3]), fmaxf(mm[2][3], mm[3][3]));

    // ---- 2. normalized coords for this block's sensor ----
    const float xs = (locs[2 * s]     - lx) / (hx - lx);
    const float ys = (locs[2 * s + 1] - ly) / (hy - ly);

    // ---- 3. cos/sin phase tables in LDS (128 threads fill 1024 entries each sensor) ----
    const float TWO_PI = 6.283185307179586f;
    for (int idx = jt; idx < KL; idx += 128) {
        int k = idx >> 5, l = idx & 31;
        float ph = TWO_PI * (xs * (float)k + ys * (float)l);
        float c, sn;
        sincosf(ph, &sn, &c);
        cosv[sensLocal][idx] = c;
        sinv[sensLocal][idx] = sn;
    }
    __syncthreads();

    // ---- 4. attn[j] = sum_kl Wr*cos + Wi*sin ----
    // Each thread streams its own contiguous 8KB row of W (L2-resident, 1MB total).
    const float4* W4 = (const float4*)(W + (size_t)jt * 2048);
    const float* cv = cosv[sensLocal];
    const float* sv = sinv[sensLocal];
    float acc = 0.0f;
#pragma unroll 4
    for (int kl = 0; kl < KL; kl += 2) {
        float4 w = W4[kl >> 1];
        acc = fmaf(w.x, cv[kl],     acc);
        acc = fmaf(w.y, sv[kl],     acc);
        acc = fmaf(w.z, cv[kl + 1], acc);
        acc = fmaf(w.w, sv[kl + 1], acc);
    }

    // ---- 5. softmax over the 128 j-threads of this sensor, then sum of softmax ----
    // 5a. max
    float m = acc;
#pragma unroll
    for (int off = 32; off; off >>= 1) m = fmaxf(m, __shfl_xor(m, off));
    if (lane == 0) wred[wave] = m;
    __syncthreads();
    m = fmaxf(wred[sensLocal * 2], wred[sensLocal * 2 + 1]);
    __syncthreads();  // protect wred before reuse

    // 5b. denom = sum exp
    float e = expf(acc - m);
    float t = e;
#pragma unroll
    for (int off = 32; off; off >>= 1) t += __shfl_xor(t, off);
    if (lane == 0) wred[wave] = t;
    __syncthreads();
    float denom = wred[sensLocal * 2] + wred[sensLocal * 2 + 1];
    __syncthreads();  // protect wred before reuse

    // 5c. scale = sum_j (e_j / denom)  (faithful to reference softmax-then-sum)
    float part = e / denom;
    t = part;
#pragma unroll
    for (int off = 32; off; off >>= 1) t += __shfl_xor(t, off);
    if (lane == 0) wred[wave] = t;
    __syncthreads();
    if (jt == 0) scale[s] = wred[sensLocal * 2] + wred[sensLocal * 2 + 1];
}

__global__ __launch_bounds__(256) void scale_x_kernel(
    const float4* __restrict__ X,
    const float* __restrict__ scale,
    float4* __restrict__ out)
{
    int i = blockIdx.x * 256 + threadIdx.x;
    const int stride = gridDim.x * 256;
    for (; i < N4; i += stride) {
        float sc = scale[i >> BT_LOG2_F4];
        float4 v = X[i];
        v.x *= sc; v.y *= sc; v.z *= sc; v.w *= sc;
        out[i] = v;
    }
}

extern "C" void kernel_launch(void* const* d_in, const int* in_sizes, int n_in,
                              void* d_out, int out_size, void* d_ws, size_t ws_size,
                              hipStream_t stream) {
    const float* X    = (const float*)d_in[0];
    const float* locs = (const float*)d_in[1];
    const float* W    = (const float*)d_in[2];
    float* out   = (float*)d_out;
    float* scale = (float*)d_ws;   // 272 floats

    scale_kernel<<<NS / 2, 256, 0, stream>>>(locs, W, scale);
    scale_x_kernel<<<2048, 256, 0, stream>>>((const float4*)X, scale, (float4*)out);
}

// Round 4
// 316.970 us; speedup vs baseline: 1.0152x; 1.0152x over previous
//
#include <hip/hip_runtime.h>
#include <hip/hip_bf16.h>

// S=272, B=128, T=1024, J=128, H=32.
// Identity: einsum('si,sjk->sjk', softmax(attn), X) = (sum_i softmax_i)[s] * X[s]
// => per-sensor scalar (≈1.0 up to fp32 rounding), then elementwise scale of X.
//
// R2 evidence: dur_us=322 with all top-5 dispatches = 85us harness poison fills
// => both kernels <85us; est. split ~50us scale_kernel + ~57us scale_x on top of
// ~215us fixed harness per-iteration work. This round attacks both kernels.
// R3 fix: __builtin_nontemporal_store needs a native clang vector, not
// HIP_vector_type<float,4> — use ext_vector_type(4).

#define NS 272
#define NJ 128
#define KL 1024          // H*H

typedef float v4f __attribute__((ext_vector_type(4)));

__global__ __launch_bounds__(256) void scale_kernel(
    const float* __restrict__ locs,   // [S,2]
    const float* __restrict__ W,      // [J,H,H,2]
    float* __restrict__ scale)        // [S] out
{
    __shared__ float4 trig[KL / 2];   // {cos(2m), sin(2m), cos(2m+1), sin(2m+1)} : 8KB
    __shared__ float mm[4][4];
    __shared__ float wredA[4], wredB[4], wredC[4];

    const int tid  = threadIdx.x;
    const int lane = tid & 63;
    const int wave = tid >> 6;
    const int s = blockIdx.x;         // one sensor per block, 272 blocks

    // ---- 1. block-wide min/max of sensor_locs ----
    float lx = 1e30f, ly = 1e30f, hx = -1e30f, hy = -1e30f;
    for (int i = tid; i < NS; i += 256) {
        float x = locs[2 * i], y = locs[2 * i + 1];
        lx = fminf(lx, x); hx = fmaxf(hx, x);
        ly = fminf(ly, y); hy = fmaxf(hy, y);
    }
#pragma unroll
    for (int off = 32; off; off >>= 1) {
        lx = fminf(lx, __shfl_xor(lx, off));
        hx = fmaxf(hx, __shfl_xor(hx, off));
        ly = fminf(ly, __shfl_xor(ly, off));
        hy = fmaxf(hy, __shfl_xor(hy, off));
    }
    if (lane == 0) { mm[wave][0] = lx; mm[wave][1] = hx; mm[wave][2] = ly; mm[wave][3] = hy; }
    __syncthreads();
    lx = fminf(fminf(mm[0][0], mm[1][0]), fminf(mm[2][0], mm[3][0]));
    hx = fmaxf(fmaxf(mm[0][1], mm[1][1]), fmaxf(mm[2][1], mm[3][1]));
    ly = fminf(fminf(mm[0][2], mm[1][2]), fminf(mm[2][2], mm[3][2]));
    hy = fmaxf(fmaxf(mm[0][3], mm[1][3]), fmaxf(mm[2][3], mm[3][3]));

    const float xs = (locs[2 * s]     - lx) / (hx - lx);
    const float ys = (locs[2 * s + 1] - ly) / (hy - ly);

    // ---- 2. trig table: float4-interleaved to mirror W's [Wr,Wi] pairs ----
    const float TWO_PI = 6.283185307179586f;
#pragma unroll
    for (int m = tid; m < KL / 2; m += 256) {
        int kl0 = 2 * m, kl1 = 2 * m + 1;
        float ph0 = TWO_PI * (xs * (float)(kl0 >> 5) + ys * (float)(kl0 & 31));
        float ph1 = TWO_PI * (xs * (float)(kl1 >> 5) + ys * (float)(kl1 & 31));
        float c0, s0, c1, s1;
        sincosf(ph0, &s0, &c0);
        sincosf(ph1, &s1, &c1);
        trig[m] = make_float4(c0, s0, c1, s1);
    }
    __syncthreads();

    // ---- 3. attn[j]: j = tid>>1, row split across thread pair (half = tid&1) ----
    const int j    = tid >> 1;
    const int half = tid & 1;
    const float4* __restrict__ W4 = (const float4*)W + (size_t)j * 512 + half * 256;
    const float4* __restrict__ T4 = trig + half * 256;
    float a0 = 0.f, a1 = 0.f, a2 = 0.f, a3 = 0.f;
#pragma unroll 8
    for (int i = 0; i < 256; ++i) {
        float4 w = W4[i];
        float4 t = T4[i];
        a0 = fmaf(w.x, t.x, a0);   // Wr * cos
        a1 = fmaf(w.y, t.y, a1);   // Wi * sin
        a2 = fmaf(w.z, t.z, a2);
        a3 = fmaf(w.w, t.w, a3);
    }
    float acc = (a0 + a1) + (a2 + a3);
    acc += __shfl_xor(acc, 1);     // combine the two halves of row j

    // ---- 4. softmax over j (each j duplicated 2x in block; sums are exactly 2x) ----
    // max
    float m = acc;
#pragma unroll
    for (int off = 32; off; off >>= 1) m = fmaxf(m, __shfl_xor(m, off));
    if (lane == 0) wredA[wave] = m;
    __syncthreads();
    m = fmaxf(fmaxf(wredA[0], wredA[1]), fmaxf(wredA[2], wredA[3]));

    // denom
    float e = expf(acc - m);
    float t = e;
#pragma unroll
    for (int off = 32; off; off >>= 1) t += __shfl_xor(t, off);
    if (lane == 0) wredB[wave] = t;
    __syncthreads();
    float denom = 0.5f * ((wredB[0] + wredB[1]) + (wredB[2] + wredB[3]));

    // sum of softmax (faithful to reference's softmax-then-sum)
    float part = e / denom;
    t = part;
#pragma unroll
    for (int off = 32; off; off >>= 1) t += __shfl_xor(t, off);
    if (lane == 0) wredC[wave] = t;
    __syncthreads();
    if (tid == 0)
        scale[s] = 0.5f * ((wredC[0] + wredC[1]) + (wredC[2] + wredC[3]));
}

// 2176 blocks = 272 sensors x 8 chunks; scale[s] is block-uniform (one scalar load).
__global__ __launch_bounds__(256) void scale_x_kernel(
    const v4f* __restrict__ X,
    const float* __restrict__ scale,
    v4f* __restrict__ out)
{
    const int bid = blockIdx.x;
    const int s = bid >> 3;
    const float sc = scale[s];
    const int base = (s << 15) + ((bid & 7) << 12) + threadIdx.x;
#pragma unroll
    for (int it = 0; it < 16; ++it) {
        int i = base + (it << 8);
        v4f v = X[i] * sc;
        __builtin_nontemporal_store(v, &out[i]);
    }
}

extern "C" void kernel_launch(void* const* d_in, const int* in_sizes, int n_in,
                              void* d_out, int out_size, void* d_ws, size_t ws_size,
                              hipStream_t stream) {
    const float* X    = (const float*)d_in[0];
    const float* locs = (const float*)d_in[1];
    const float* W    = (const float*)d_in[2];
    float* out   = (float*)d_out;
    float* scale = (float*)d_ws;   // 272 floats of scratch

    scale_kernel<<<NS, 256, 0, stream>>>(locs, W, scale);
    scale_x_kernel<<<NS * 8, 256, 0, stream>>>((const v4f*)X, scale, (v4f*)out);
}